// Round 11
// baseline (183.333 us; speedup 1.0000x reference)
//
#include <hip/hip_runtime.h>

#define FDIM 16
#define RPB  32     // rows per block
#define NT   256    // threads = 32 groups x 8 lanes
#define CAP  1024   // LDS edge-tile capacity (block span ~512 expected)

// ---------------------------------------------------------------------------
// Wave-parallel lower_bound on the sorted rows array: returns first index e
// with rows[e] >= target. All 64 lanes of the calling wave participate.
// Each round narrows the range 64x via one gather + ballot (<=5 rounds).
// ---------------------------------------------------------------------------
__device__ __forceinline__ int lower_bound_wave(const int* __restrict__ rows,
                                                int nedge, int target, int lane) {
  int lo = 0, hi = nedge;   // invariant: rows[e]<target for e<lo; >=target for e>=hi
  while (hi > lo) {
    int step = (hi - lo + 63) >> 6;
    int idx = lo + lane * step;
    bool pred = (idx < hi) && (rows[idx] < target);
    unsigned long long m = __ballot(pred);
    if (m == 0ULL) { hi = lo; break; }          // rows[lo] >= target -> s = lo
    int j = 63 - __builtin_clzll(m);            // highest probe below target
    int nlo = lo + j * step + 1;
    int nhi = (j < 63) ? min(lo + (j + 1) * step, hi) : hi;
    lo = nlo; hi = nhi;                         // range shrinks to < step
  }
  return lo;
}

// ---------------------------------------------------------------------------
// Single fused kernel: CSR-less SpMM + GCNII epilogue.
// Block = 256 threads = 32 groups x 8 lanes; lane = feature pair {2l,2l+1}.
// Block's edge span [s_blk,t_blk) found by wave-parallel binary search on the
// sorted rows array (no row_ptr pass). Edge tile (rows,cols,vals) staged
// coalesced in LDS; tile edges split EVENLY across 32 groups; register
// run-accumulate with row-change flush into lhi[32][16] via LDS atomics;
// in-register epilogue per group.
// NOTE (r7-r10 evidence): the x-gather runs at the device's random-64B-line
// request-rate ceiling (~50G lines/s); structure changes don't move it.
// ---------------------------------------------------------------------------
__global__ __launch_bounds__(NT) void spmm_fuse_kernel(
    const int* __restrict__ rows,
    const int* __restrict__ cols,
    const float* __restrict__ vals,
    const float* __restrict__ x,
    const float* __restrict__ h0,
    const float* __restrict__ weight,
    const float* __restrict__ fc_w,
    const float* __restrict__ fc_b,
    const float* __restrict__ lamda,
    const int* __restrict__ lpar,
    float* __restrict__ out,
    int n, int nedge) {
  __shared__ float wsh[2 * FDIM * FDIM];   // 2 KB weight
  __shared__ int   lr[CAP];                // 4 KB local row idx
  __shared__ int   lc[CAP];                // 4 KB cols
  __shared__ float lv[CAP];                // 4 KB vals
  __shared__ float lhi[RPB][FDIM];         // 2 KB accumulators
  __shared__ int   sbounds[2];

  int tid = (int)threadIdx.x;
  int R0 = blockIdx.x * RPB;
  int Rend = min(R0 + RPB, n);

  if (tid < 64) {   // wave 0: find the block's edge span
    int sb = lower_bound_wave(rows, nedge, R0, tid);
    int tb = lower_bound_wave(rows, nedge, Rend, tid);
    if (tid == 0) { sbounds[0] = sb; sbounds[1] = tb; }
  }
  for (int i = tid; i < 2 * FDIM * FDIM; i += NT) wsh[i] = weight[i];
  for (int i = tid; i < RPB * FDIM; i += NT) ((float*)lhi)[i] = 0.f;
  __syncthreads();

  int s_blk = sbounds[0];
  int t_blk = sbounds[1];

  int g = tid >> 3;    // group 0..31
  int l = tid & 7;     // lane 0..7
  const float2* __restrict__ x2 = reinterpret_cast<const float2*>(x);

  for (int t0 = s_blk; t0 < t_blk; t0 += CAP) {
    int t1 = min(t0 + CAP, t_blk);
    int len = t1 - t0;
    for (int i = tid; i < len; i += NT) {
      lr[i] = rows[t0 + i] - R0;   // coalesced; localized row index
      lc[i] = cols[t0 + i];
      lv[i] = vals[t0 + i];
    }
    __syncthreads();

    int a = (len * g) >> 5;        // even split among 32 groups
    int b = (len * (g + 1)) >> 5;
    if (a < b) {
      int cur = lr[a];
      float ax = 0.f, ay = 0.f;

#define FLUSH()                                   \
      { atomicAdd(&lhi[cur][2 * l],     ax);      \
        atomicAdd(&lhi[cur][2 * l + 1], ay);      \
        ax = 0.f; ay = 0.f; }
#define STEP(r_, v_, gx_, gy_)                    \
      if (r_ != cur) { FLUSH(); cur = r_; }       \
      ax = fmaf(v_, gx_, ax);                     \
      ay = fmaf(v_, gy_, ay);

      int e = a;
      for (; e + 8 <= b; e += 8) {
        int   r0 = lr[e+0], r1 = lr[e+1], r2 = lr[e+2], r3 = lr[e+3];
        int   r4 = lr[e+4], r5 = lr[e+5], r6 = lr[e+6], r7 = lr[e+7];
        int   c0 = lc[e+0], c1 = lc[e+1], c2 = lc[e+2], c3 = lc[e+3];
        int   c4 = lc[e+4], c5 = lc[e+5], c6 = lc[e+6], c7 = lc[e+7];
        float v0 = lv[e+0], v1 = lv[e+1], v2 = lv[e+2], v3 = lv[e+3];
        float v4 = lv[e+4], v5 = lv[e+5], v6 = lv[e+6], v7 = lv[e+7];
        float2 g0 = x2[(size_t)c0 * 8 + l], g1 = x2[(size_t)c1 * 8 + l];
        float2 g2 = x2[(size_t)c2 * 8 + l], g3 = x2[(size_t)c3 * 8 + l];
        float2 g4 = x2[(size_t)c4 * 8 + l], g5 = x2[(size_t)c5 * 8 + l];
        float2 g6 = x2[(size_t)c6 * 8 + l], g7 = x2[(size_t)c7 * 8 + l];
        if (r7 == cur) {  // whole chunk same row (sorted)
          ax = fmaf(v0, g0.x, ax); ay = fmaf(v0, g0.y, ay);
          ax = fmaf(v1, g1.x, ax); ay = fmaf(v1, g1.y, ay);
          ax = fmaf(v2, g2.x, ax); ay = fmaf(v2, g2.y, ay);
          ax = fmaf(v3, g3.x, ax); ay = fmaf(v3, g3.y, ay);
          ax = fmaf(v4, g4.x, ax); ay = fmaf(v4, g4.y, ay);
          ax = fmaf(v5, g5.x, ax); ay = fmaf(v5, g5.y, ay);
          ax = fmaf(v6, g6.x, ax); ay = fmaf(v6, g6.y, ay);
          ax = fmaf(v7, g7.x, ax); ay = fmaf(v7, g7.y, ay);
        } else {
          STEP(r0, v0, g0.x, g0.y)
          STEP(r1, v1, g1.x, g1.y)
          STEP(r2, v2, g2.x, g2.y)
          STEP(r3, v3, g3.x, g3.y)
          STEP(r4, v4, g4.x, g4.y)
          STEP(r5, v5, g5.x, g5.y)
          STEP(r6, v6, g6.x, g6.y)
          STEP(r7, v7, g7.x, g7.y)
        }
      }
      for (; e < b; ++e) {
        int rr_ = lr[e];
        float2 gg = x2[(size_t)lc[e] * 8 + l];
        STEP(rr_, lv[e], gg.x, gg.y)
      }
      FLUSH();
#undef STEP
#undef FLUSH
    }
    __syncthreads();   // slice consumption done before next tile overwrite
  }

  __syncthreads();     // lhi final before epilogue reads

  int r = R0 + g;
  if (r >= n) return;

  float2 hi2 = make_float2(lhi[g][2 * l], lhi[g][2 * l + 1]);
  float2 h02 = reinterpret_cast<const float2*>(h0)[(size_t)r * 8 + l];
  float2 xf2 = reinterpret_cast<const float2*>(x)[(size_t)r * 8 + l];
  float theta = logf(lamda[0] / (float)lpar[0] + 1.0f);

  // alpha = hi . fc_w + fc_b  (8-lane reduce over feature pairs)
  float av = hi2.x * fc_w[2 * l] + hi2.y * fc_w[2 * l + 1];
  av += __shfl_xor(av, 1, 8);
  av += __shfl_xor(av, 2, 8);
  av += __shfl_xor(av, 4, 8);
  float alpha = av + fc_b[0];

  // s[f] = sum_k hi[k]*W[k,f] + h0[k]*W[16+k,f]   (f = 2l, 2l+1)
  const float2* wsh2 = reinterpret_cast<const float2*>(wsh);
  float sx = 0.f, sy = 0.f;
#pragma unroll
  for (int k = 0; k < FDIM; ++k) {
    float hk  = lhi[g][k];                                   // LDS broadcast
    float h0k = (k & 1) ? __shfl(h02.y, k >> 1, 8)
                        : __shfl(h02.x, k >> 1, 8);
    float2 w1 = wsh2[k * 8 + l];
    float2 w2 = wsh2[(FDIM + k) * 8 + l];
    sx = fmaf(hk, w1.x, sx);  sy = fmaf(hk, w1.y, sy);
    sx = fmaf(h0k, w2.x, sx); sy = fmaf(h0k, w2.y, sy);
  }

  float rx = (1.f - alpha) * hi2.x + alpha * h02.x;
  float ry = (1.f - alpha) * hi2.y + alpha * h02.y;
  float2 o;
  o.x = fmaf(theta, sx, (1.f - theta) * rx) + xf2.x;
  o.y = fmaf(theta, sy, (1.f - theta) * ry) + xf2.y;
  reinterpret_cast<float2*>(out)[(size_t)r * 8 + l] = o;
}

extern "C" void kernel_launch(void* const* d_in, const int* in_sizes, int n_in,
                              void* d_out, int out_size, void* d_ws, size_t ws_size,
                              hipStream_t stream) {
  const float* x        = (const float*)d_in[0];
  const float* h0       = (const float*)d_in[1];
  const int* adj_row    = (const int*)d_in[2];   // int32 (JAX x64 disabled)
  const int* adj_col    = (const int*)d_in[3];   // int32
  const float* adj_val  = (const float*)d_in[4];
  const float* weight   = (const float*)d_in[5];
  const float* fc_w     = (const float*)d_in[6];
  const float* fc_b     = (const float*)d_in[7];
  const float* lamda    = (const float*)d_in[8];
  const int* lpar       = (const int*)d_in[9];

  int n = in_sizes[0] / FDIM;
  int nedge = in_sizes[2];
  float* out = (float*)d_out;

  int sb = (n + RPB - 1) / RPB;
  spmm_fuse_kernel<<<sb, NT, 0, stream>>>(adj_row, adj_col, adj_val, x, h0,
                                          weight, fc_w, fc_b, lamda, lpar,
                                          out, n, nedge);
}

// Round 12
// 170.946 us; speedup vs baseline: 1.0725x; 1.0725x over previous
//
#include <hip/hip_runtime.h>

#define FDIM 16
#define RPB  32     // rows per block
#define NT   256    // threads = 32 groups x 8 lanes
#define CAP  1024   // LDS edge-tile capacity (block span ~512 expected)

// ---------------------------------------------------------------------------
// Kernel A: per-block-boundary lower_bound on the sorted rows array.
// bounds[b] = first edge index e with rows[e] >= b*RPB;  bounds[nblocks]=nedge.
// One thread per boundary (~15.6k threads, 23 probes each; upper search
// levels are shared across threads -> L2-hot; ~10 MB distinct traffic vs the
// 32 MB full rows scan of the old rowptr kernel).
// ---------------------------------------------------------------------------
__global__ __launch_bounds__(256) void bounds_kernel(const int* __restrict__ rows,
                                                     int* __restrict__ bounds,
                                                     int nedge, int nblocks) {
  int b = blockIdx.x * blockDim.x + threadIdx.x;
  if (b > nblocks) return;
  int target = b * RPB;
  int lo = 0, hi = nedge;
  while (lo < hi) {
    int mid = (lo + hi) >> 1;
    if (rows[mid] < target) lo = mid + 1; else hi = mid;
  }
  bounds[b] = lo;
}

// ---------------------------------------------------------------------------
// Kernel B: fused SpMM + GCNII epilogue (r8/r10 measured-best structure).
// Block = 256 threads = 32 groups x 8 lanes; lane = feature pair {2l,2l+1}.
// Edge tile (rows,cols,vals) staged coalesced in LDS; tile edges split
// EVENLY across 32 groups; register run-accumulate with row-change flush
// into lhi[32][16] via LDS atomics; in-register epilogue per group.
// r7-r11 evidence: the x-gather runs at the device's random-64B-line
// request-rate ceiling (~50G lines/s, 8M lines -> ~160us); structure
// changes do not move it. Only aux work is tunable.
// ---------------------------------------------------------------------------
__global__ __launch_bounds__(NT) void spmm_fuse_kernel(
    const int* __restrict__ bounds,
    const int* __restrict__ rows,
    const int* __restrict__ cols,
    const float* __restrict__ vals,
    const float* __restrict__ x,
    const float* __restrict__ h0,
    const float* __restrict__ weight,
    const float* __restrict__ fc_w,
    const float* __restrict__ fc_b,
    const float* __restrict__ lamda,
    const int* __restrict__ lpar,
    float* __restrict__ out,
    int n) {
  __shared__ float wsh[2 * FDIM * FDIM];   // 2 KB weight
  __shared__ int   lr[CAP];                // 4 KB local row idx
  __shared__ int   lc[CAP];                // 4 KB cols
  __shared__ float lv[CAP];                // 4 KB vals
  __shared__ float lhi[RPB][FDIM];         // 2 KB accumulators

  int tid = (int)threadIdx.x;
  int R0 = blockIdx.x * RPB;
  for (int i = tid; i < 2 * FDIM * FDIM; i += NT) wsh[i] = weight[i];
  for (int i = tid; i < RPB * FDIM; i += NT) ((float*)lhi)[i] = 0.f;
  __syncthreads();

  int s_blk = bounds[blockIdx.x];
  int t_blk = bounds[blockIdx.x + 1];

  int g = tid >> 3;    // group 0..31
  int l = tid & 7;     // lane 0..7
  const float2* __restrict__ x2 = reinterpret_cast<const float2*>(x);

  for (int t0 = s_blk; t0 < t_blk; t0 += CAP) {
    int t1 = min(t0 + CAP, t_blk);
    int len = t1 - t0;
    for (int i = tid; i < len; i += NT) {
      lr[i] = rows[t0 + i] - R0;   // coalesced; localized row index
      lc[i] = cols[t0 + i];
      lv[i] = vals[t0 + i];
    }
    __syncthreads();

    int a = (len * g) >> 5;        // even split among 32 groups
    int b = (len * (g + 1)) >> 5;
    if (a < b) {
      int cur = lr[a];
      float ax = 0.f, ay = 0.f;

#define FLUSH()                                   \
      { atomicAdd(&lhi[cur][2 * l],     ax);      \
        atomicAdd(&lhi[cur][2 * l + 1], ay);      \
        ax = 0.f; ay = 0.f; }
#define STEP(r_, v_, gx_, gy_)                    \
      if (r_ != cur) { FLUSH(); cur = r_; }       \
      ax = fmaf(v_, gx_, ax);                     \
      ay = fmaf(v_, gy_, ay);

      int e = a;
      for (; e + 8 <= b; e += 8) {
        int   r0 = lr[e+0], r1 = lr[e+1], r2 = lr[e+2], r3 = lr[e+3];
        int   r4 = lr[e+4], r5 = lr[e+5], r6 = lr[e+6], r7 = lr[e+7];
        int   c0 = lc[e+0], c1 = lc[e+1], c2 = lc[e+2], c3 = lc[e+3];
        int   c4 = lc[e+4], c5 = lc[e+5], c6 = lc[e+6], c7 = lc[e+7];
        float v0 = lv[e+0], v1 = lv[e+1], v2 = lv[e+2], v3 = lv[e+3];
        float v4 = lv[e+4], v5 = lv[e+5], v6 = lv[e+6], v7 = lv[e+7];
        float2 g0 = x2[(size_t)c0 * 8 + l], g1 = x2[(size_t)c1 * 8 + l];
        float2 g2 = x2[(size_t)c2 * 8 + l], g3 = x2[(size_t)c3 * 8 + l];
        float2 g4 = x2[(size_t)c4 * 8 + l], g5 = x2[(size_t)c5 * 8 + l];
        float2 g6 = x2[(size_t)c6 * 8 + l], g7 = x2[(size_t)c7 * 8 + l];
        if (r7 == cur) {  // whole chunk same row (sorted)
          ax = fmaf(v0, g0.x, ax); ay = fmaf(v0, g0.y, ay);
          ax = fmaf(v1, g1.x, ax); ay = fmaf(v1, g1.y, ay);
          ax = fmaf(v2, g2.x, ax); ay = fmaf(v2, g2.y, ay);
          ax = fmaf(v3, g3.x, ax); ay = fmaf(v3, g3.y, ay);
          ax = fmaf(v4, g4.x, ax); ay = fmaf(v4, g4.y, ay);
          ax = fmaf(v5, g5.x, ax); ay = fmaf(v5, g5.y, ay);
          ax = fmaf(v6, g6.x, ax); ay = fmaf(v6, g6.y, ay);
          ax = fmaf(v7, g7.x, ax); ay = fmaf(v7, g7.y, ay);
        } else {
          STEP(r0, v0, g0.x, g0.y)
          STEP(r1, v1, g1.x, g1.y)
          STEP(r2, v2, g2.x, g2.y)
          STEP(r3, v3, g3.x, g3.y)
          STEP(r4, v4, g4.x, g4.y)
          STEP(r5, v5, g5.x, g5.y)
          STEP(r6, v6, g6.x, g6.y)
          STEP(r7, v7, g7.x, g7.y)
        }
      }
      for (; e < b; ++e) {
        int rr_ = lr[e];
        float2 gg = x2[(size_t)lc[e] * 8 + l];
        STEP(rr_, lv[e], gg.x, gg.y)
      }
      FLUSH();
#undef STEP
#undef FLUSH
    }
    __syncthreads();   // slice consumption done before next tile overwrite
  }

  __syncthreads();     // lhi final before epilogue reads

  int r = R0 + g;
  if (r >= n) return;

  float2 hi2 = make_float2(lhi[g][2 * l], lhi[g][2 * l + 1]);
  float2 h02 = reinterpret_cast<const float2*>(h0)[(size_t)r * 8 + l];
  float2 xf2 = reinterpret_cast<const float2*>(x)[(size_t)r * 8 + l];
  float theta = logf(lamda[0] / (float)lpar[0] + 1.0f);

  // alpha = hi . fc_w + fc_b  (8-lane reduce over feature pairs)
  float av = hi2.x * fc_w[2 * l] + hi2.y * fc_w[2 * l + 1];
  av += __shfl_xor(av, 1, 8);
  av += __shfl_xor(av, 2, 8);
  av += __shfl_xor(av, 4, 8);
  float alpha = av + fc_b[0];

  // s[f] = sum_k hi[k]*W[k,f] + h0[k]*W[16+k,f]   (f = 2l, 2l+1)
  const float2* wsh2 = reinterpret_cast<const float2*>(wsh);
  float sx = 0.f, sy = 0.f;
#pragma unroll
  for (int k = 0; k < FDIM; ++k) {
    float hk  = lhi[g][k];                                   // LDS broadcast
    float h0k = (k & 1) ? __shfl(h02.y, k >> 1, 8)
                        : __shfl(h02.x, k >> 1, 8);
    float2 w1 = wsh2[k * 8 + l];
    float2 w2 = wsh2[(FDIM + k) * 8 + l];
    sx = fmaf(hk, w1.x, sx);  sy = fmaf(hk, w1.y, sy);
    sx = fmaf(h0k, w2.x, sx); sy = fmaf(h0k, w2.y, sy);
  }

  float rx = (1.f - alpha) * hi2.x + alpha * h02.x;
  float ry = (1.f - alpha) * hi2.y + alpha * h02.y;
  float2 o;
  o.x = fmaf(theta, sx, (1.f - theta) * rx) + xf2.x;
  o.y = fmaf(theta, sy, (1.f - theta) * ry) + xf2.y;
  reinterpret_cast<float2*>(out)[(size_t)r * 8 + l] = o;
}

extern "C" void kernel_launch(void* const* d_in, const int* in_sizes, int n_in,
                              void* d_out, int out_size, void* d_ws, size_t ws_size,
                              hipStream_t stream) {
  const float* x        = (const float*)d_in[0];
  const float* h0       = (const float*)d_in[1];
  const int* adj_row    = (const int*)d_in[2];   // int32 (JAX x64 disabled)
  const int* adj_col    = (const int*)d_in[3];   // int32
  const float* adj_val  = (const float*)d_in[4];
  const float* weight   = (const float*)d_in[5];
  const float* fc_w     = (const float*)d_in[6];
  const float* fc_b     = (const float*)d_in[7];
  const float* lamda    = (const float*)d_in[8];
  const int* lpar       = (const int*)d_in[9];

  int n = in_sizes[0] / FDIM;
  int nedge = in_sizes[2];
  float* out = (float*)d_out;
  int* bounds = (int*)d_ws;              // nblocks+1 ints (~62 KB)

  int nblocks = (n + RPB - 1) / RPB;
  int bb = (nblocks + 1 + 255) / 256;
  bounds_kernel<<<bb, 256, 0, stream>>>(adj_row, bounds, nedge, nblocks);

  spmm_fuse_kernel<<<nblocks, NT, 0, stream>>>(bounds, adj_row, adj_col,
                                               adj_val, x, h0, weight, fc_w,
                                               fc_b, lamda, lpar, out, n);
}